// Round 8
// baseline (44.802 us; speedup 1.0000x reference)
//
#include <hip/hip_runtime.h>
#include <math.h>

namespace {

constexpr int kB = 16384;  // batch rows
constexpr int kD = 512;    // feature dim
constexpr int kC = 1000;   // classes
constexpr float kScale = 64.f;                     // center pre-scale for fp8
constexpr float kC2 = (1.f / 64.f) * 1.44269504f;  // unscale folded into exp2

typedef __attribute__((ext_vector_type(4))) float f4v;  // MFMA acc
typedef long long i64b;                                  // fp8 MFMA operand
union BU { uint4 v; i64b d[2]; };

// pack 4 f32 -> 4 fp8 e4m3 (OCP) bytes in a u32
__device__ inline unsigned int pk4(float a, float b, float c, float d) {
  int r = __builtin_amdgcn_cvt_pk_fp8_f32(a, b, 0, false);
  r = __builtin_amdgcn_cvt_pk_fp8_f32(c, d, r, true);
  return (unsigned int)r;
}

// --- k_prep: column-norm + fp8 B-fragments (x64) + f32 cn[1024][512] -----
// 65 blocks x 256 threads; block = one 16-col class tile (tile 63+ zero).
// pb[tile][kp 0..7][lane][16B]: lo 8B = frag ks=2kp, hi 8B = ks=2kp+1;
// frag elem j -> center[ks*32+(lane>>4)*8+j][tile*16+(lane&15)] * inv * 64.
__global__ __launch_bounds__(256)
void k_prep(const float* __restrict__ center, unsigned char* __restrict__ pb,
            float* __restrict__ cn, float* __restrict__ out) {
  if (blockIdx.x == 0 && threadIdx.x == 0) out[0] = 0.f;  // zero accumulator
  __shared__ float Ct[kD][16];  // 32 KB
  __shared__ float P[16][16];
  __shared__ float inv[16];     // UNscaled 1/||c||
  const int t = threadIdx.x, ct = blockIdx.x;
  const int col = t & 15, dg = t >> 4;
  const int cc = ct * 16 + col;
  float s = 0.f;
#pragma unroll 8
  for (int j = 0; j < 32; ++j) {
    int d = dg * 32 + j;
    float v = (cc < kC) ? center[(size_t)d * kC + cc] : 0.f;
    Ct[d][col] = v;
    s = fmaf(v, v, s);
  }
  P[dg][col] = s;
  __syncthreads();
  if (t < 16) {
    float tot = 0.f;
#pragma unroll
    for (int j = 0; j < 16; ++j) tot += P[j][t];
    inv[t] = rsqrtf(fmaxf(tot, 1e-24f));  // == 1/max(||c||,1e-12)
  }
  __syncthreads();
  // normalized f32 transposed copy for the z side-channel
  if (ct < 64) {
    float iv = inv[col];
#pragma unroll
    for (int j = 0; j < 32; ++j)
      cn[(size_t)cc * kD + dg * 32 + j] = Ct[dg * 32 + j][col] * iv;
  }
  // fp8 fragments (x64 scale kills e4m3 subnormals)
#pragma unroll
  for (int pi = 0; pi < 4; ++pi) {
    int p = t * 4 + pi;            // 1024 (ks,lane) fragment-slots
    int ks = p >> 6, lane = p & 63;
    int cl = lane & 15, d0 = ks * 32 + ((lane >> 4) << 3);
    float iv = inv[cl] * kScale;
    unsigned int lo = pk4(Ct[d0 + 0][cl] * iv, Ct[d0 + 1][cl] * iv,
                          Ct[d0 + 2][cl] * iv, Ct[d0 + 3][cl] * iv);
    unsigned int hi = pk4(Ct[d0 + 4][cl] * iv, Ct[d0 + 5][cl] * iv,
                          Ct[d0 + 6][cl] * iv, Ct[d0 + 7][cl] * iv);
    *(uint2*)(pb + (size_t)ct * 8192 + (ks >> 1) * 1024 + lane * 16 + (ks & 1) * 8) =
        make_uint2(lo, hi);
  }
}

// --- k_main: 64-row pinned-A fp8 + 8-slot B-ring + z side-channel --------
// 256 blocks x 512 threads (8 waves, 2/SIMD). Block = 64 rows; wave w owns
// class tiles w*8..+8 and ALL 64 rows (A in 128 pinned VGPRs). Per B-load:
// 8 MFMA -> ring distance 6 covers ~234 cyc > L2 latency. z computed in f32
// during staging (Σz only needs the block sum), so the hot loop is maskless.
__global__ __launch_bounds__(512, 2)
void k_main(const float* __restrict__ features,
            const int* __restrict__ labels,
            const unsigned char* __restrict__ pb,
            const float* __restrict__ cn,
            float* __restrict__ out) {
  __shared__ __align__(16) unsigned char Ab[64 * kD];  // 32 KB fp8, swizzled
  __shared__ float Sl[64][8];  // per-(row,wave) softmax-denominator partials
  __shared__ float Zw[8];      // per-wave z partial sums
  const int t = threadIdx.x;
  const int w = t >> 6, lane = t & 63;
  const int b0r = blockIdx.x * 64;

  // stage 64x512 f32 -> fp8 -> LDS (8B-granule XOR swizzle) + f32 z-partial
  float zp = 0.f;
#pragma unroll
  for (int i = 0; i < 8; ++i) {
    int ci = i * 512 + t;
    int row = ci >> 6, kc = ci & 63;
    const float* src = features + (size_t)(b0r + row) * kD + kc * 8;
    float4 f0 = *(const float4*)src;
    float4 f1 = *(const float4*)(src + 4);
    const float* cnp = cn + (size_t)labels[b0r + row] * kD + kc * 8;
    float4 c0 = *(const float4*)cnp;
    float4 c1 = *(const float4*)(cnp + 4);
    zp += f0.x * c0.x + f0.y * c0.y + f0.z * c0.z + f0.w * c0.w +
          f1.x * c1.x + f1.y * c1.y + f1.z * c1.z + f1.w * c1.w;
    unsigned int lo = pk4(f0.x, f0.y, f0.z, f0.w);
    unsigned int hi = pk4(f1.x, f1.y, f1.z, f1.w);
    *(uint2*)(Ab + row * 512 + ((kc * 8) ^ ((row & 7) << 3))) = make_uint2(lo, hi);
  }
  zp += __shfl_xor(zp, 1, 64);
  zp += __shfl_xor(zp, 2, 64);
  zp += __shfl_xor(zp, 4, 64);
  zp += __shfl_xor(zp, 8, 64);
  zp += __shfl_xor(zp, 16, 64);
  zp += __shfl_xor(zp, 32, 64);
  if (lane == 0) Zw[w] = zp;
  __syncthreads();

  // load 64 rows x K=512 of A into 128 VGPRs, then PIN them
  i64b a8[4][16];
#pragma unroll
  for (int rt = 0; rt < 4; ++rt) {
    const int row = rt * 16 + (lane & 15);
    const int rb = row * 512, swz = (row & 7) << 3;
#pragma unroll
    for (int ks = 0; ks < 16; ++ks) {
      const int kc = ks * 4 + (lane >> 4);
      a8[rt][ks] = *(const i64b*)(Ab + rb + ((kc * 8) ^ swz));
    }
  }
#pragma unroll
  for (int rt = 0; rt < 4; ++rt)
#pragma unroll
    for (int ks = 0; ks < 16; ++ks)
      asm volatile("" : "+v"(a8[rt][ks]));

  float l[16];
#pragma unroll
  for (int s = 0; s < 16; ++s) l[s] = 0.f;

  // B ring: step = i*8+p; slot p; prefetch distance 6 (6 loads in flight).
  // Max prefetch tile = w*8+8 <= 64 -> covered by padded 65th tile.
  const unsigned char* pbw = pb + (size_t)(w * 8) * 8192 + lane * 16;
  uint4 br[8];
#pragma unroll
  for (int p = 0; p < 6; ++p) br[p] = *(const uint4*)(pbw + p * 1024);

#pragma unroll 1
  for (int i = 0; i < 8; ++i) {
    const unsigned char* pcur = pbw + (size_t)i * 8192;
    const int cls = (w * 8 + i) * 16 + (lane & 15);
    const float bias = (cls < kC) ? 0.f : -1e30f;  // tile-uniform mask

    f4v acc[4][2] = {{{0,0,0,0},{0,0,0,0}}, {{0,0,0,0},{0,0,0,0}},
                     {{0,0,0,0},{0,0,0,0}}, {{0,0,0,0},{0,0,0,0}}};
#pragma unroll
    for (int p = 0; p < 8; ++p) {
      {  // prefetch step i*8+p+6 into slot (p+6)&7
        const int pp = p + 6;
        br[pp & 7] = *(const uint4*)(pcur + (pp >> 3) * 8192 + (pp & 7) * 1024);
      }
      BU b; b.v = br[p];
      __builtin_amdgcn_s_setprio(1);
#pragma unroll
      for (int rt = 0; rt < 4; ++rt) {
        acc[rt][0] = __builtin_amdgcn_mfma_f32_16x16x32_fp8_fp8(
            a8[rt][2 * p], b.d[0], acc[rt][0], 0, 0, 0);
        acc[rt][1] = __builtin_amdgcn_mfma_f32_16x16x32_fp8_fp8(
            a8[rt][2 * p + 1], b.d[1], acc[rt][1], 0, 0, 0);
      }
      __builtin_amdgcn_s_setprio(0);
    }

    // maskless fold: add + fma(bias) + exp2 + add per logit
#pragma unroll
    for (int rt = 0; rt < 4; ++rt)
#pragma unroll
      for (int r = 0; r < 4; ++r) {
        float lg = acc[rt][0][r] + acc[rt][1][r];
        l[rt * 4 + r] += exp2f(fmaf(lg, kC2, bias));
      }
  }

  // merge 16 lanes of each quarter, publish L per (row, wave)
#pragma unroll
  for (int s = 0; s < 16; ++s) {
    float L = l[s];
    L += __shfl_xor(L, 1, 64);
    L += __shfl_xor(L, 2, 64);
    L += __shfl_xor(L, 4, 64);
    L += __shfl_xor(L, 8, 64);
    if ((lane & 15) == 0) {
      const int row = (s >> 2) * 16 + ((lane >> 4) << 2) + (s & 3);
      Sl[row][w] = L;
    }
  }
  __syncthreads();

  // first 64 threads: row each -> log(denominator); block-reduce; - z; atomic
  if (t < 64) {
    float L = 0.f;
#pragma unroll
    for (int j = 0; j < 8; ++j) L += Sl[t][j];
    float nll = __logf(L);
    nll += __shfl_xor(nll, 1, 64);
    nll += __shfl_xor(nll, 2, 64);
    nll += __shfl_xor(nll, 4, 64);
    nll += __shfl_xor(nll, 8, 64);
    nll += __shfl_xor(nll, 16, 64);
    nll += __shfl_xor(nll, 32, 64);
    if (t == 0) {
      float Z = 0.f;
#pragma unroll
      for (int j = 0; j < 8; ++j) Z += Zw[j];
      atomicAdd(out, (nll - Z) * (1.0f / (float)kB));
    }
  }
}

}  // namespace

extern "C" void kernel_launch(void* const* d_in, const int* in_sizes, int n_in,
                              void* d_out, int out_size, void* d_ws, size_t ws_size,
                              hipStream_t stream) {
  const float* features = (const float*)d_in[0];
  const int* labels     = (const int*)d_in[1];
  const float* center   = (const float*)d_in[2];
  float* out = (float*)d_out;

  unsigned char* pb = (unsigned char*)d_ws;                  // 65 * 8 KB
  float* cn = (float*)((char*)d_ws + 65 * 8192);             // 1024*512 f32 = 2 MB

  k_prep<<<65, 256, 0, stream>>>(center, pb, cn, out);
  k_main<<<kB / 64, 512, 0, stream>>>(features, labels, pb, cn, out);
}